// Round 1
// baseline (681.312 us; speedup 1.0000x reference)
//
#include <hip/hip_runtime.h>
#include <hip/hip_bf16.h>

#define N_ 8
#define C_ 256
#define HW_ 4096
#define CNT_ (C_*HW_)

typedef __attribute__((ext_vector_type(8))) short bf16x8;
typedef __attribute__((ext_vector_type(4))) float f32x4;

__device__ inline unsigned short f2bf(float f){
  union{float f; unsigned u;} v; v.f=f;
  unsigned r = v.u + 0x7fff + ((v.u>>16)&1);
  return (unsigned short)(r>>16);
}

__device__ inline f32x4 mfma16(bf16x8 a, bf16x8 b, f32x4 c){
  return __builtin_amdgcn_mfma_f32_16x16x32_bf16(a,b,c,0,0,0);
}

// ---------------- weight convert (fp32 -> bf16) ----------------
__global__ void k_cvt(const float* __restrict__ src, unsigned short* __restrict__ dst){
  int i = blockIdx.x*256 + threadIdx.x;
  dst[i] = f2bf(src[i]);
}

// ---------------- layernorm stats, stage 1 ----------------
__global__ void k_stats1(const float* __restrict__ x, float2* __restrict__ part){
  int n = blockIdx.x >> 8;
  int chunk = blockIdx.x & 255;
  const float4* p = (const float4*)(x + (size_t)n*CNT_ + (size_t)chunk*4096);
  int t = threadIdx.x;
  float s=0.f, s2=0.f;
  #pragma unroll
  for(int i=0;i<4;i++){
    float4 v = p[t + 256*i];
    s  += v.x+v.y+v.z+v.w;
    s2 += v.x*v.x+v.y*v.y+v.z*v.z+v.w*v.w;
  }
  #pragma unroll
  for(int o=32;o;o>>=1){ s += __shfl_down(s,o); s2 += __shfl_down(s2,o); }
  __shared__ float sh[4], sh2[4];
  int lane = t&63, wid = t>>6;
  if(lane==0){ sh[wid]=s; sh2[wid]=s2; }
  __syncthreads();
  if(t==0){
    float2 r; r.x = sh[0]+sh[1]+sh[2]+sh[3]; r.y = sh2[0]+sh2[1]+sh2[2]+sh2[3];
    part[blockIdx.x] = r;
  }
}

// ---------------- layernorm stats, stage 2 ----------------
__global__ void k_stats2(const float2* __restrict__ part, float2* __restrict__ stats){
  int n = blockIdx.x, t = threadIdx.x;
  float2 v = part[n*256 + t];
  float s = v.x, s2 = v.y;
  #pragma unroll
  for(int o=32;o;o>>=1){ s += __shfl_down(s,o); s2 += __shfl_down(s2,o); }
  __shared__ float sh[4], sh2[4];
  int lane = t&63, wid = t>>6;
  if(lane==0){ sh[wid]=s; sh2[wid]=s2; }
  __syncthreads();
  if(t==0){
    s = sh[0]+sh[1]+sh[2]+sh[3];
    s2 = sh2[0]+sh2[1]+sh2[2]+sh2[3];
    float mean = s * (1.f/(float)CNT_);
    float var  = s2 * (1.f/(float)CNT_) - mean*mean;
    float2 r; r.x = mean; r.y = rsqrtf(var + 1e-5f);
    stats[n] = r;
  }
}

// ---------------- normalize + transpose to NHWC bf16 ----------------
// grid (64 p-tiles, 4 c-tiles, 8 batches), 256 threads
__global__ void k_norm(const float* __restrict__ x, const float* __restrict__ lnw,
                       const float* __restrict__ lnb, const float2* __restrict__ stats,
                       unsigned short* __restrict__ nx){
  __shared__ float tile[64][65];
  int n = blockIdx.z, c0 = blockIdx.y*64, p0 = blockIdx.x*64;
  float2 st = stats[n];
  float mu = st.x, rs = st.y;
  int t = threadIdx.x, col = t&63, rw = t>>6;
  #pragma unroll
  for(int pass=0; pass<16; pass++){
    int row = pass*4 + rw;
    size_t gi = (size_t)(c0+row)*HW_ + (p0+col);
    float v = x[(size_t)n*CNT_ + gi];
    tile[row][col] = (v - mu)*rs*lnw[gi] + lnb[gi];
  }
  __syncthreads();
  #pragma unroll
  for(int pass=0; pass<16; pass++){
    int prow = pass*4 + rw;
    nx[((size_t)n*HW_ + p0+prow)*C_ + c0 + col] = f2bf(tile[col][prow]);
  }
}

// ---------------- strip GEMM: D[row][col] = sum_k A[row][k]*B[col][k] + bias ----------------
// A,B row-major with ld=256 (K=256). Each wave: 16 rows x 64 cols.
__global__ void k_gemm(const unsigned short* __restrict__ Abase, long strideA,
                       const unsigned short* __restrict__ Bbase, long strideB,
                       const float* __restrict__ bias, int bias_row,
                       unsigned short* __restrict__ Out, long strideO, int ldo){
  int n = blockIdx.z;
  const unsigned short* A = Abase + (size_t)n*strideA;
  const unsigned short* B = Bbase + (size_t)n*strideB;
  unsigned short* O = Out + (size_t)n*strideO;
  int t = threadIdx.x, w = t>>6, l = t&63, ri = l&15, k8 = (l>>4)*8;
  int row0 = blockIdx.x*64 + w*16;
  int col0 = blockIdx.y*64;
  f32x4 zero = {0.f,0.f,0.f,0.f};
  f32x4 acc[4] = {zero, zero, zero, zero};
  for(int k=0;k<256;k+=32){
    bf16x8 a = *(const bf16x8*)(A + (size_t)(row0+ri)*256 + k + k8);
    #pragma unroll
    for(int j=0;j<4;j++){
      bf16x8 b = *(const bf16x8*)(B + (size_t)(col0+j*16+ri)*256 + k + k8);
      acc[j] = mfma16(a,b,acc[j]);
    }
  }
  #pragma unroll
  for(int j=0;j<4;j++){
    #pragma unroll
    for(int r=0;r<4;r++){
      int row = row0 + (l>>4)*4 + r;
      int col = col0 + j*16 + ri;
      float d = acc[j][r] + (bias_row ? bias[row] : bias[col]);
      O[(size_t)row*ldo + col] = f2bf(d);
    }
  }
}

// ---------------- flash attention ----------------
// grid (64 q-blocks, 8 batches), 256 threads; wave w owns 16 queries
__global__ __launch_bounds__(256) void k_attn(const unsigned short* __restrict__ qt,
                                              const unsigned short* __restrict__ kt,
                                              const unsigned short* __restrict__ vv,
                                              unsigned short* __restrict__ rest){
  __shared__ unsigned short Klds[32][264];
  __shared__ unsigned short Vlds[256][40];
  __shared__ unsigned short Plds[4][16][40];
  int nb = blockIdx.y;
  int t = threadIdx.x, w = t>>6, l = t&63, ri = l&15, k8 = (l>>4)*8;
  int i0 = blockIdx.x*64 + w*16;
  const unsigned short* qbase = qt + (size_t)nb*HW_*C_;
  const unsigned short* kbase = kt + (size_t)nb*HW_*C_;
  const unsigned short* vbase = vv + (size_t)nb*C_*HW_;
  bf16x8 qf[8];
  #pragma unroll
  for(int kk=0;kk<8;kk++)
    qf[kk] = *(const bf16x8*)(qbase + (size_t)(i0+ri)*256 + kk*32 + k8);
  f32x4 zero = {0.f,0.f,0.f,0.f};
  f32x4 o[16];
  #pragma unroll
  for(int ct=0;ct<16;ct++) o[ct] = zero;
  float m[4], lsum[4];
  #pragma unroll
  for(int r=0;r<4;r++){ m[r] = -1e30f; lsum[r] = 0.f; }
  const float scale = 0.0625f;

  for(int j0=0;j0<HW_;j0+=32){
    // stage K tile [32][256]
    #pragma unroll
    for(int cc=0;cc<4;cc++){
      int cid = cc*256 + t;
      int row = cid >> 5, coff = (cid&31)*8;
      *(bf16x8*)(&Klds[row][coff]) = *(const bf16x8*)(kbase + (size_t)(j0+row)*256 + coff);
    }
    // stage V tile [256][32]
    #pragma unroll
    for(int cc=0;cc<4;cc++){
      int cid = cc*256 + t;
      int row = cid >> 2, coff = (cid&3)*8;
      *(bf16x8*)(&Vlds[row][coff]) = *(const bf16x8*)(vbase + (size_t)row*HW_ + j0 + coff);
    }
    __syncthreads();
    // S = Q K^T  (two 16-col subtiles)
    f32x4 s0 = zero, s1 = zero;
    #pragma unroll
    for(int kk=0;kk<8;kk++){
      bf16x8 b0 = *(const bf16x8*)(&Klds[ri][kk*32+k8]);
      bf16x8 b1 = *(const bf16x8*)(&Klds[16+ri][kk*32+k8]);
      s0 = mfma16(qf[kk], b0, s0);
      s1 = mfma16(qf[kk], b1, s1);
    }
    // online softmax per row r
    float p0v[4], p1v[4];
    #pragma unroll
    for(int r=0;r<4;r++){
      float sa = s0[r]*scale, sb = s1[r]*scale;
      float mx = fmaxf(sa, sb);
      #pragma unroll
      for(int off=1;off<16;off<<=1) mx = fmaxf(mx, __shfl_xor(mx, off));
      float mn = fmaxf(m[r], mx);
      float alpha = __expf(m[r] - mn);
      float pa = __expf(sa - mn), pb = __expf(sb - mn);
      float rs = pa + pb;
      #pragma unroll
      for(int off=1;off<16;off<<=1) rs += __shfl_xor(rs, off);
      lsum[r] = lsum[r]*alpha + rs;
      m[r] = mn;
      p0v[r] = pa; p1v[r] = pb;
      #pragma unroll
      for(int ct=0;ct<16;ct++) o[ct][r] *= alpha;
    }
    // P -> LDS (D-layout write, A-layout read)
    #pragma unroll
    for(int r=0;r<4;r++){
      int prow = (l>>4)*4 + r;
      Plds[w][prow][ri]      = f2bf(p0v[r]);
      Plds[w][prow][16+ri]   = f2bf(p1v[r]);
    }
    bf16x8 pa = *(const bf16x8*)(&Plds[w][ri][k8]);
    #pragma unroll
    for(int ct=0;ct<16;ct++){
      bf16x8 b = *(const bf16x8*)(&Vlds[ct*16+ri][k8]);
      o[ct] = mfma16(pa, b, o[ct]);
    }
    __syncthreads();
  }
  // epilogue: divide by lsum, store bf16 [seq][dim]
  unsigned short* rbase = rest + ((size_t)nb*HW_ + i0)*C_;
  #pragma unroll
  for(int r=0;r<4;r++){
    float inv = 1.f/lsum[r];
    int row = (l>>4)*4 + r;
    #pragma unroll
    for(int ct=0;ct<16;ct++)
      rbase[(size_t)row*C_ + ct*16 + ri] = f2bf(o[ct][r]*inv);
  }
}

// ---------------- output projection + residual (fp32 out) ----------------
// grid (4, 64, 8): out[n][c][p] = x + sum_in Wo[c][in]*rest[p][in] + bo[c]
__global__ void k_outproj(const unsigned short* __restrict__ wob,
                          const unsigned short* __restrict__ rest,
                          const float* __restrict__ bo, const float* __restrict__ x,
                          float* __restrict__ out){
  int n = blockIdx.z;
  const unsigned short* B = rest + (size_t)n*HW_*C_;
  int t = threadIdx.x, w = t>>6, l = t&63, ri = l&15, k8 = (l>>4)*8;
  int row0 = blockIdx.x*64 + w*16;
  int col0 = blockIdx.y*64;
  f32x4 zero = {0.f,0.f,0.f,0.f};
  f32x4 acc[4] = {zero, zero, zero, zero};
  for(int k=0;k<256;k+=32){
    bf16x8 a = *(const bf16x8*)(wob + (size_t)(row0+ri)*256 + k + k8);
    #pragma unroll
    for(int j=0;j<4;j++){
      bf16x8 b = *(const bf16x8*)(B + (size_t)(col0+j*16+ri)*256 + k + k8);
      acc[j] = mfma16(a,b,acc[j]);
    }
  }
  #pragma unroll
  for(int j=0;j<4;j++){
    #pragma unroll
    for(int r=0;r<4;r++){
      int row = row0 + (l>>4)*4 + r;
      int col = col0 + j*16 + ri;
      size_t idx = ((size_t)n*C_ + row)*HW_ + col;
      out[idx] = acc[j][r] + bo[row] + x[idx];
    }
  }
}

extern "C" void kernel_launch(void* const* d_in, const int* in_sizes, int n_in,
                              void* d_out, int out_size, void* d_ws, size_t ws_size,
                              hipStream_t stream) {
  const float* x   = (const float*)d_in[0];
  const float* lnw = (const float*)d_in[1];
  const float* lnb = (const float*)d_in[2];
  const float* wq  = (const float*)d_in[3];
  const float* bq  = (const float*)d_in[4];
  const float* wk  = (const float*)d_in[5];
  const float* bk  = (const float*)d_in[6];
  const float* wv  = (const float*)d_in[7];
  const float* bv  = (const float*)d_in[8];
  const float* wo  = (const float*)d_in[9];
  const float* bo  = (const float*)d_in[10];
  float* out = (float*)d_out;

  uintptr_t base = (uintptr_t)d_ws;
  float2* part  = (float2*)base;                       // 16384 B
  float2* stats = (float2*)(base + 16384);             // 64 B
  unsigned short* wqb = (unsigned short*)(base + 16448);
  unsigned short* wkb = wqb + 65536;
  unsigned short* wvb = wqb + 2*65536;
  unsigned short* wob = wqb + 3*65536;
  unsigned short* nx  = wqb + 4*65536;                 // 8*4096*256 bf16 = 16 MB
  const size_t TEN = (size_t)N_*HW_*C_;                // 8,388,608 elems
  unsigned short* qtb = nx + TEN;
  unsigned short* ktb = qtb + TEN;
  unsigned short* vvb = ktb + TEN;
  unsigned short* rest = nx;                           // alias: nx dead after QKV

  k_cvt<<<dim3(256),256,0,stream>>>(wq, wqb);
  k_cvt<<<dim3(256),256,0,stream>>>(wk, wkb);
  k_cvt<<<dim3(256),256,0,stream>>>(wv, wvb);
  k_cvt<<<dim3(256),256,0,stream>>>(wo, wob);

  k_stats1<<<dim3(2048),256,0,stream>>>(x, part);
  k_stats2<<<dim3(8),256,0,stream>>>(part, stats);
  k_norm<<<dim3(64,4,8),256,0,stream>>>(x, lnw, lnb, stats, nx);

  // Q,K: [seq][dim] = nx[seq][k] . W[col][k];  V: [dim][seq] = Wv[row][k] . nx[col][k]
  k_gemm<<<dim3(64,4,8),256,0,stream>>>(nx, (long)TEN/N_ * 0 + (long)(HW_*C_), wqb, 0, bq, 0, qtb, (long)(HW_*C_), C_);
  k_gemm<<<dim3(64,4,8),256,0,stream>>>(nx, (long)(HW_*C_), wkb, 0, bk, 0, ktb, (long)(HW_*C_), C_);
  k_gemm<<<dim3(4,64,8),256,0,stream>>>(wvb, 0, nx, (long)(HW_*C_), bv, 1, vvb, (long)(C_*HW_), HW_);

  k_attn<<<dim3(64,8),256,0,stream>>>(qtb, ktb, vvb, rest);

  k_outproj<<<dim3(4,64,8),256,0,stream>>>(wob, rest, bo, x, out);
}

// Round 2
// 409.098 us; speedup vs baseline: 1.6654x; 1.6654x over previous
//
#include <hip/hip_runtime.h>
#include <hip/hip_bf16.h>

#define N_ 8
#define C_ 256
#define HW_ 4096
#define CNT_ (C_*HW_)

typedef __attribute__((ext_vector_type(8))) short bf16x8;
typedef __attribute__((ext_vector_type(4))) float f32x4;
typedef __attribute__((ext_vector_type(16))) float f32x16;

__device__ inline unsigned short f2bf(float f){
  union{float f; unsigned u;} v; v.f=f;
  unsigned r = v.u + 0x7fff + ((v.u>>16)&1);
  return (unsigned short)(r>>16);
}

__device__ inline f32x4 mfma16(bf16x8 a, bf16x8 b, f32x4 c){
  return __builtin_amdgcn_mfma_f32_16x16x32_bf16(a,b,c,0,0,0);
}
__device__ inline f32x16 mfma32(bf16x8 a, bf16x8 b, f32x16 c){
  return __builtin_amdgcn_mfma_f32_32x32x16_bf16(a,b,c,0,0,0);
}

#define GLL16(gp, lp) __builtin_amdgcn_global_load_lds( \
    (__attribute__((address_space(1))) void*)(gp), \
    (__attribute__((address_space(3))) void*)(lp), 16, 0, 0)

// ---------------- weight convert (fp32 -> bf16) ----------------
__global__ void k_cvt(const float* __restrict__ src, unsigned short* __restrict__ dst){
  int i = blockIdx.x*256 + threadIdx.x;
  dst[i] = f2bf(src[i]);
}

// ---------------- layernorm stats, stage 1 ----------------
__global__ void k_stats1(const float* __restrict__ x, float2* __restrict__ part){
  int n = blockIdx.x >> 8;
  int chunk = blockIdx.x & 255;
  const float4* p = (const float4*)(x + (size_t)n*CNT_ + (size_t)chunk*4096);
  int t = threadIdx.x;
  float s=0.f, s2=0.f;
  #pragma unroll
  for(int i=0;i<4;i++){
    float4 v = p[t + 256*i];
    s  += v.x+v.y+v.z+v.w;
    s2 += v.x*v.x+v.y*v.y+v.z*v.z+v.w*v.w;
  }
  #pragma unroll
  for(int o=32;o;o>>=1){ s += __shfl_down(s,o); s2 += __shfl_down(s2,o); }
  __shared__ float sh[4], sh2[4];
  int lane = t&63, wid = t>>6;
  if(lane==0){ sh[wid]=s; sh2[wid]=s2; }
  __syncthreads();
  if(t==0){
    float2 r; r.x = sh[0]+sh[1]+sh[2]+sh[3]; r.y = sh2[0]+sh2[1]+sh2[2]+sh2[3];
    part[blockIdx.x] = r;
  }
}

// ---------------- layernorm stats, stage 2 ----------------
__global__ void k_stats2(const float2* __restrict__ part, float2* __restrict__ stats){
  int n = blockIdx.x, t = threadIdx.x;
  float2 v = part[n*256 + t];
  float s = v.x, s2 = v.y;
  #pragma unroll
  for(int o=32;o;o>>=1){ s += __shfl_down(s,o); s2 += __shfl_down(s2,o); }
  __shared__ float sh[4], sh2[4];
  int lane = t&63, wid = t>>6;
  if(lane==0){ sh[wid]=s; sh2[wid]=s2; }
  __syncthreads();
  if(t==0){
    s = sh[0]+sh[1]+sh[2]+sh[3];
    s2 = sh2[0]+sh2[1]+sh2[2]+sh2[3];
    float mean = s * (1.f/(float)CNT_);
    float var  = s2 * (1.f/(float)CNT_) - mean*mean;
    float2 r; r.x = mean; r.y = rsqrtf(var + 1e-5f);
    stats[n] = r;
  }
}

// ---------------- normalize + transpose to NHWC bf16 ----------------
__global__ void k_norm(const float* __restrict__ x, const float* __restrict__ lnw,
                       const float* __restrict__ lnb, const float2* __restrict__ stats,
                       unsigned short* __restrict__ nx){
  __shared__ float tile[64][65];
  int n = blockIdx.z, c0 = blockIdx.y*64, p0 = blockIdx.x*64;
  float2 st = stats[n];
  float mu = st.x, rs = st.y;
  int t = threadIdx.x, col = t&63, rw = t>>6;
  #pragma unroll
  for(int pass=0; pass<16; pass++){
    int row = pass*4 + rw;
    size_t gi = (size_t)(c0+row)*HW_ + (p0+col);
    float v = x[(size_t)n*CNT_ + gi];
    tile[row][col] = (v - mu)*rs*lnw[gi] + lnb[gi];
  }
  __syncthreads();
  #pragma unroll
  for(int pass=0; pass<16; pass++){
    int prow = pass*4 + rw;
    nx[((size_t)n*HW_ + p0+prow)*C_ + c0 + col] = f2bf(tile[col][prow]);
  }
}

// ---------------- strip GEMM: D[row][col] = (sum_k A[row][k]*B[col][k] + bias)*scale ----
__global__ void k_gemm(const unsigned short* __restrict__ Abase, long strideA,
                       const unsigned short* __restrict__ Bbase, long strideB,
                       const float* __restrict__ bias, int bias_row, float scale,
                       unsigned short* __restrict__ Out, long strideO, int ldo){
  int n = blockIdx.z;
  const unsigned short* A = Abase + (size_t)n*strideA;
  const unsigned short* B = Bbase + (size_t)n*strideB;
  unsigned short* O = Out + (size_t)n*strideO;
  int t = threadIdx.x, w = t>>6, l = t&63, ri = l&15, k8 = (l>>4)*8;
  int row0 = blockIdx.x*64 + w*16;
  int col0 = blockIdx.y*64;
  f32x4 zero = {0.f,0.f,0.f,0.f};
  f32x4 acc[4] = {zero, zero, zero, zero};
  for(int k=0;k<256;k+=32){
    bf16x8 a = *(const bf16x8*)(A + (size_t)(row0+ri)*256 + k + k8);
    #pragma unroll
    for(int j=0;j<4;j++){
      bf16x8 b = *(const bf16x8*)(B + (size_t)(col0+j*16+ri)*256 + k + k8);
      acc[j] = mfma16(a,b,acc[j]);
    }
  }
  #pragma unroll
  for(int j=0;j<4;j++){
    #pragma unroll
    for(int r=0;r<4;r++){
      int row = row0 + (l>>4)*4 + r;
      int col = col0 + j*16 + ri;
      float d = (acc[j][r] + (bias_row ? bias[row] : bias[col]))*scale;
      O[(size_t)row*ldo + col] = f2bf(d);
    }
  }
}

// ---------------- flash attention, 32x32 MFMA, swapped operands ----------------
// 256 blocks x 512 threads. 8 waves = 2 j-streams x 4 q-strips (32 q each).
// K LDS: [stream][buf][32 rows x 512B], XOR-slot swizzled (staged via gll pre-swizzled src)
// V LDS: [stream][buf][256 rows x 80B (64B data + 16B pad)]
__device__ inline void stage_tiles(const char* kb, const char* vb, char* lds,
                                   int w, int l, int itx, int buf){
  int hi = l>>5, lo5 = l&31;
  #pragma unroll
  for(int k=0;k<4;k++){
    int g = w*4+k, s = g>>4, i = g&15;
    int row = 2*i + hi;
    int j = s*2048 + itx*32 + row;
    const char* src = kb + ((size_t)j<<9) + (((lo5 ^ row)&31)<<4);
    char* dst = lds + ((s*2+buf)<<14) + (i<<10);
    GLL16(src, dst);
  }
  #pragma unroll
  for(int k=0;k<5;k++){
    int g = w*5+k; int s = (g>=20) ? 1 : 0; int i = g - s*20;
    int c = i*64 + l;
    int d = c/5; int sg = c - d*5; if(sg==4) sg=0;
    int j0 = s*2048 + itx*32;
    const char* src = vb + ((size_t)d<<13) + ((size_t)j0<<1) + (sg<<4);
    char* dst = lds + 65536 + (s*2+buf)*20480 + i*1024;
    GLL16(src, dst);
  }
}

__global__ __launch_bounds__(512, 2) void k_attn2(const unsigned short* __restrict__ qt,
                                                  const unsigned short* __restrict__ kt,
                                                  const unsigned short* __restrict__ vv,
                                                  unsigned short* __restrict__ rest){
  __shared__ __align__(16) char lds[147456];
  int t = threadIdx.x, w = t>>6, l = t&63, hi = l>>5, lo5 = l&31;
  int nb = blockIdx.x & 7, qb = blockIdx.x >> 3;
  int st = w & 3, sm = w >> 2;
  int q0 = qb*128 + st*32;
  const char* kb = (const char*)(kt + (size_t)nb*HW_*C_);
  const char* vb = (const char*)(vv + (size_t)nb*C_*HW_);
  const char* qp = (const char*)(qt + (size_t)nb*HW_*C_);

  bf16x8 qf[16];
  #pragma unroll
  for(int ds=0; ds<16; ds++)
    qf[ds] = *(const bf16x8*)(qp + ((size_t)(q0+lo5)<<9) + ds*32 + hi*16);

  f32x16 o[8];
  #pragma unroll
  for(int dt=0;dt<8;dt++){
    #pragma unroll
    for(int r=0;r<16;r++) o[dt][r]=0.f;
  }
  float m = -1e30f, lsum = 0.f;

  stage_tiles(kb, vb, lds, w, l, 0, 0);
  __syncthreads();

  for(int it=0; it<64; ++it){
    int cur = it & 1;
    if (it < 63) stage_tiles(kb, vb, lds, w, l, it+1, cur^1);
    const char* Kc = lds + ((sm*2+cur)<<14);
    const char* Vc = lds + 65536 + (sm*2+cur)*20480;

    // QK^T : S[j][q], lane holds q = lo5, 16 j-rows via regs (swapped operands)
    f32x16 S;
    #pragma unroll
    for(int r=0;r<16;r++) S[r]=0.f;
    #pragma unroll
    for(int ds=0; ds<16; ds++){
      bf16x8 kf = *(const bf16x8*)(Kc + (lo5<<9) + (((((ds<<1)|hi)) ^ lo5)<<4));
      S = mfma32(kf, qf[ds], S);
    }

    // online softmax: per-lane q, in-lane + lane^32 reduce
    float mx = fmaxf(S[0], S[1]);
    #pragma unroll
    for(int r=2;r<16;r++) mx = fmaxf(mx, S[r]);
    mx = fmaxf(mx, __shfl_xor(mx, 32));
    if (!__all(mx <= m + 8.f)){
      float mn = fmaxf(m, mx);
      float al = __expf(m - mn);
      lsum *= al;
      #pragma unroll
      for(int dt=0;dt<8;dt++) o[dt] = o[dt] * al;
      m = mn;
    }
    unsigned pk[8];
    float rs = 0.f;
    #pragma unroll
    for(int tt=0;tt<8;tt++){
      float pa = __expf(S[2*tt]-m), pb = __expf(S[2*tt+1]-m);
      rs += pa + pb;
      pk[tt] = (unsigned)f2bf(pa) | ((unsigned)f2bf(pb)<<16);
    }
    rs += __shfl_xor(rs, 32);
    lsum += rs;

    // build PV A-operand fragments (P[q][j-slice]) from lane-local P via cross-half shuffle
    unsigned xk[8];
    #pragma unroll
    for(int tt=0;tt<8;tt++) xk[tt] = (unsigned)__shfl_xor((int)pk[tt], 32);
    bool hb = (l & 32) != 0;
    union { unsigned u[4]; bf16x8 v; } F0, F1;
    F0.u[0] = hb ? xk[2] : pk[0];
    F0.u[1] = hb ? xk[3] : pk[1];
    F0.u[2] = hb ? pk[2] : xk[0];
    F0.u[3] = hb ? pk[3] : xk[1];
    F1.u[0] = hb ? xk[6] : pk[4];
    F1.u[1] = hb ? xk[7] : pk[5];
    F1.u[2] = hb ? pk[6] : xk[4];
    F1.u[3] = hb ? pk[7] : xk[5];

    // PV: O^T[d][q] += V[d][j] * P[q][j]  (lane holds q = lo5 -> per-lane alpha/lsum)
    #pragma unroll
    for(int dt=0;dt<8;dt++){
      bf16x8 v0 = *(const bf16x8*)(Vc + (dt*32+lo5)*80 + hi*16);
      o[dt] = mfma32(v0, F0.v, o[dt]);
      bf16x8 v1 = *(const bf16x8*)(Vc + (dt*32+lo5)*80 + 32 + hi*16);
      o[dt] = mfma32(v1, F1.v, o[dt]);
    }
    __syncthreads();
  }

  // in-block merge of the two j-streams, then write rest[q][d] bf16
  float* mlf = (float*)(lds + 133120);
  if (sm == 1){
    char* base = lds + st*33280 + lo5*1040;
    #pragma unroll
    for(int dt=0;dt<8;dt++){
      #pragma unroll
      for(int g=0;g<4;g++){
        float4 v4; v4.x=o[dt][4*g]; v4.y=o[dt][4*g+1]; v4.z=o[dt][4*g+2]; v4.w=o[dt][4*g+3];
        *(float4*)(base + (dt*32 + g*8 + hi*4)*4) = v4;
      }
    }
    if (l < 32){ mlf[st*64 + lo5] = m; mlf[st*64 + 32 + lo5] = lsum; }
  }
  __syncthreads();
  if (sm == 0){
    float m1 = mlf[st*64 + lo5], l1 = mlf[st*64 + 32 + lo5];
    float mN = fmaxf(m, m1);
    float a0 = __expf(m - mN), a1 = __expf(m1 - mN);
    float inv = 1.f/(lsum*a0 + l1*a1);
    const char* base = lds + st*33280 + lo5*1040;
    unsigned short* rb = rest + ((size_t)nb*HW_ + q0 + lo5)*C_;
    #pragma unroll
    for(int dt=0;dt<8;dt++){
      #pragma unroll
      for(int g=0;g<4;g++){
        float4 o1 = *(const float4*)(base + (dt*32+g*8+hi*4)*4);
        int d0 = dt*32 + g*8 + hi*4;
        unsigned short h0 = f2bf((o[dt][4*g]*a0   + o1.x*a1)*inv);
        unsigned short h1 = f2bf((o[dt][4*g+1]*a0 + o1.y*a1)*inv);
        unsigned short h2 = f2bf((o[dt][4*g+2]*a0 + o1.z*a1)*inv);
        unsigned short h3 = f2bf((o[dt][4*g+3]*a0 + o1.w*a1)*inv);
        uint2 uo; uo.x = (unsigned)h0 | ((unsigned)h1<<16);
        uo.y = (unsigned)h2 | ((unsigned)h3<<16);
        *(uint2*)(rb + d0) = uo;
      }
    }
  }
}

// ---------------- output projection + residual (fp32 out) ----------------
__global__ void k_outproj(const unsigned short* __restrict__ wob,
                          const unsigned short* __restrict__ rest,
                          const float* __restrict__ bo, const float* __restrict__ x,
                          float* __restrict__ out){
  int n = blockIdx.z;
  const unsigned short* B = rest + (size_t)n*HW_*C_;
  int t = threadIdx.x, w = t>>6, l = t&63, ri = l&15, k8 = (l>>4)*8;
  int row0 = blockIdx.x*64 + w*16;
  int col0 = blockIdx.y*64;
  f32x4 zero = {0.f,0.f,0.f,0.f};
  f32x4 acc[4] = {zero, zero, zero, zero};
  for(int k=0;k<256;k+=32){
    bf16x8 a = *(const bf16x8*)(wob + (size_t)(row0+ri)*256 + k + k8);
    #pragma unroll
    for(int j=0;j<4;j++){
      bf16x8 b = *(const bf16x8*)(B + (size_t)(col0+j*16+ri)*256 + k + k8);
      acc[j] = mfma16(a,b,acc[j]);
    }
  }
  #pragma unroll
  for(int j=0;j<4;j++){
    #pragma unroll
    for(int r=0;r<4;r++){
      int row = row0 + (l>>4)*4 + r;
      int col = col0 + j*16 + ri;
      size_t idx = ((size_t)n*C_ + row)*HW_ + col;
      out[idx] = acc[j][r] + bo[row] + x[idx];
    }
  }
}

extern "C" void kernel_launch(void* const* d_in, const int* in_sizes, int n_in,
                              void* d_out, int out_size, void* d_ws, size_t ws_size,
                              hipStream_t stream) {
  const float* x   = (const float*)d_in[0];
  const float* lnw = (const float*)d_in[1];
  const float* lnb = (const float*)d_in[2];
  const float* wq  = (const float*)d_in[3];
  const float* bq  = (const float*)d_in[4];
  const float* wk  = (const float*)d_in[5];
  const float* bk  = (const float*)d_in[6];
  const float* wv  = (const float*)d_in[7];
  const float* bv  = (const float*)d_in[8];
  const float* wo  = (const float*)d_in[9];
  const float* bo  = (const float*)d_in[10];
  float* out = (float*)d_out;

  uintptr_t base = (uintptr_t)d_ws;
  float2* part  = (float2*)base;
  float2* stats = (float2*)(base + 16384);
  unsigned short* wqb = (unsigned short*)(base + 16448);
  unsigned short* wkb = wqb + 65536;
  unsigned short* wvb = wqb + 2*65536;
  unsigned short* wob = wqb + 3*65536;
  unsigned short* nx  = wqb + 4*65536;
  const size_t TEN = (size_t)N_*HW_*C_;
  unsigned short* qtb = nx + TEN;
  unsigned short* ktb = qtb + TEN;
  unsigned short* vvb = ktb + TEN;
  unsigned short* rest = nx;

  k_cvt<<<dim3(256),256,0,stream>>>(wq, wqb);
  k_cvt<<<dim3(256),256,0,stream>>>(wk, wkb);
  k_cvt<<<dim3(256),256,0,stream>>>(wv, wvb);
  k_cvt<<<dim3(256),256,0,stream>>>(wo, wob);

  k_stats1<<<dim3(2048),256,0,stream>>>(x, part);
  k_stats2<<<dim3(8),256,0,stream>>>(part, stats);
  k_norm<<<dim3(64,4,8),256,0,stream>>>(x, lnw, lnb, stats, nx);

  // Q (pre-scaled by 1/16), K: [seq][dim];  V: [dim][seq]
  k_gemm<<<dim3(64,4,8),256,0,stream>>>(nx, (long)(HW_*C_), wqb, 0, bq, 0, 0.0625f, qtb, (long)(HW_*C_), C_);
  k_gemm<<<dim3(64,4,8),256,0,stream>>>(nx, (long)(HW_*C_), wkb, 0, bk, 0, 1.0f, ktb, (long)(HW_*C_), C_);
  k_gemm<<<dim3(4,64,8),256,0,stream>>>(wvb, 0, nx, (long)(HW_*C_), bv, 1, 1.0f, vvb, (long)(C_*HW_), HW_);

  k_attn2<<<dim3(256),512,0,stream>>>(qtb, ktb, vvb, rest);

  k_outproj<<<dim3(4,64,8),256,0,stream>>>(wob, rest, bo, x, out);
}